// Round 2
// baseline (230.224 us; speedup 1.0000x reference)
//
#include <hip/hip_runtime.h>

// Problem constants (fixed by the reference).
#define NS 4
#define NA 8192
#define NTOK 1024
#define NC 8
#define THREADS 256
#define JSLOTS 4
#define JPB (THREADS * JSLOTS)   // 1024 j-atoms per block
#define TI 128                   // i-atoms per block
#define NJB (NA / JPB)           // 8
#define NIB (NA / TI)            // 64
#define NBLOCKS (NIB * NJB * NS) // 2048

// ws layout: counts[NS*NC*NC] ints, then done[1] int. Zeroed via hipMemsetAsync.

__global__ __launch_bounds__(THREADS, 8)
void clash_kernel(const float* __restrict__ coords, const int* __restrict__ asym,
                  const int* __restrict__ a2t, int* __restrict__ counts,
                  int* __restrict__ done, float* __restrict__ out) {
  __shared__ float4 tile[TI];     // (2x, 2y, 2z, sq - thr^2) per i-atom
  __shared__ int tchain[TI];
  __shared__ int red[NC * NC];
  __shared__ int hist[NC];
  __shared__ int lastflag;

  const int tid = threadIdx.x;
  const int ib = blockIdx.x, jb = blockIdx.y, s = blockIdx.z;
  if (tid < NC * NC) red[tid] = 0;

  const float* __restrict__ base = coords + (size_t)s * NA * 3;
  const float THR2 = 1.21f;  // 1.1^2

  // Per-thread j-atoms (4 slots, stride 256)
  float xj[JSLOTS], yj[JSLOTS], zj[JSLOTS], tj[JSLOTS];
  int bj[JSLOTS];
#pragma unroll
  for (int u = 0; u < JSLOTS; ++u) {
    int j = jb * JPB + u * THREADS + tid;
    float x = base[3 * j + 0], y = base[3 * j + 1], z = base[3 * j + 2];
    xj[u] = x; yj[u] = y; zj[u] = z;
    tj[u] = x * x + y * y + z * z;
    bj[u] = asym[a2t[j]];
  }
  // Stage i-tile (chain ids computed in-block; no precompute kernel)
  if (tid < TI) {
    int i = ib * TI + tid;
    float x = base[3 * i + 0], y = base[3 * i + 1], z = base[3 * i + 2];
    tile[tid] = make_float4(2.0f * x, 2.0f * y, 2.0f * z, x * x + y * y + z * z - THR2);
    tchain[tid] = asym[a2t[i]];
  }
  __syncthreads();

  // clash  <=>  d2 < thr2  <=>  2*dot - (sq_i - thr2) > sq_j
  for (int k0 = 0; k0 < TI; k0 += 64) {
    int my_a = tchain[k0 + (tid & 63)];
    int a0 = __builtin_amdgcn_readfirstlane(my_a);
    if (__all(my_a == a0)) {
      // chain_i uniform over this 64-i run: chain-agnostic accumulators (4 VGPRs)
      int acc[JSLOTS];
#pragma unroll
      for (int u = 0; u < JSLOTS; ++u) acc[u] = 0;
#pragma unroll 8
      for (int t = 0; t < 64; ++t) {
        float4 ci = tile[k0 + t];
#pragma unroll
        for (int u = 0; u < JSLOTS; ++u) {
          float d = fmaf(ci.x, xj[u], fmaf(ci.y, yj[u], fmaf(ci.z, zj[u], -ci.w)));
          acc[u] += (d > tj[u]);
        }
      }
      // merge: wave butterfly + one LDS atomic per slot (b uniform in practice)
#pragma unroll
      for (int u = 0; u < JSLOTS; ++u) {
        int v = acc[u];
        int b0 = __builtin_amdgcn_readfirstlane(bj[u]);
        if (__all(bj[u] == b0)) {
#pragma unroll
          for (int m = 32; m >= 1; m >>= 1) v += __shfl_xor(v, m, 64);
          if ((tid & 63) == 0 && v) atomicAdd(&red[a0 * NC + b0], v);
        } else {
          if (v) atomicAdd(&red[a0 * NC + bj[u]], v);
        }
      }
    } else {
      // rare robustness path: mixed i-chains within the 64-run
      for (int t = 0; t < 64; ++t) {
        int a = tchain[k0 + t];
        float4 ci = tile[k0 + t];
#pragma unroll
        for (int u = 0; u < JSLOTS; ++u) {
          float d = fmaf(ci.x, xj[u], fmaf(ci.y, yj[u], fmaf(ci.z, zj[u], -ci.w)));
          if (d > tj[u]) atomicAdd(&red[a * NC + bj[u]], 1);
        }
      }
    }
  }

  __syncthreads();
  if (tid < NC * NC) {
    int v = red[tid];
    if (v) atomicAdd(&counts[s * NC * NC + tid], v);
  }

  // ---- completion: last block finalizes (device-scope atomics + fences) ----
  __threadfence();
  __syncthreads();
  if (tid == 0)
    lastflag = (atomicAdd(done, 1) == NBLOCKS - 1);
  __syncthreads();
  if (!lastflag) return;

  __threadfence();  // acquire: all blocks' count atomics now visible via L2
  if (tid < NC) hist[tid] = 0;
  __syncthreads();
  for (int t = tid; t < NTOK; t += THREADS) atomicAdd(&hist[asym[t]], NA / NTOK);
  __syncthreads();

  // tid = s*64 + a*8 + b  (256 threads cover all entries)
  int c = atomicAdd(&counts[tid], 0);  // device-scope coherent read
  int a = (tid >> 3) & 7, b = tid & 7;
  float total = (a == b) ? 0.0f : (float)c;
  float minn = (float)min(hist[a], hist[b]);
  float rel = total / minn;
  out[tid] = ((total > 100.0f) || (rel > 0.5f)) ? 1.0f : 0.0f;
  out[256 + 2 * tid + 0] = total;
  out[256 + 2 * tid + 1] = rel;
}

extern "C" void kernel_launch(void* const* d_in, const int* in_sizes, int n_in,
                              void* d_out, int out_size, void* d_ws, size_t ws_size,
                              hipStream_t stream) {
  const float* coords = (const float*)d_in[0];  // [4, 8192, 3] f32
  const int* asym = (const int*)d_in[1];        // [1024] i32
  const int* a2t = (const int*)d_in[2];         // [8192] i32
  float* out = (float*)d_out;                   // 256 flags + 512 details

  int* counts = (int*)d_ws;            // [4*8*8]
  int* done = counts + NS * NC * NC;   // [1]

  hipMemsetAsync(d_ws, 0, (NS * NC * NC + 1) * sizeof(int), stream);
  clash_kernel<<<dim3(NIB, NJB, NS), THREADS, 0, stream>>>(coords, asym, a2t,
                                                           counts, done, out);
}

// Round 3
// 93.543 us; speedup vs baseline: 2.4612x; 2.4612x over previous
//
#include <hip/hip_runtime.h>

// Problem constants (fixed by the reference).
#define NS 4
#define NA 8192
#define NTOK 1024
#define NC 8
#define THREADS 256
#define JSLOTS 8
#define JPB (THREADS * JSLOTS)   // 2048 j-atoms per block
#define TI 128                   // i-atoms per block (within one chain segment)
#define NJB (NA / JPB)           // 4
#define NIB (NA / TI)            // 64

// ws: counts[NS*NC*NC] ints, zeroed via hipMemsetAsync before clash_kernel.

__global__ __launch_bounds__(THREADS, 4)
void clash_kernel(const float* __restrict__ coords, const int* __restrict__ asym,
                  const int* __restrict__ a2t, int* __restrict__ counts) {
  __shared__ float4 tile[TI];     // (2x, 2y, 2z, thr^2 - sq) per i-atom
  __shared__ int tchain[TI];
  __shared__ int red[NC * NC];

  const int tid = threadIdx.x;
  const int ib = blockIdx.x, jb = blockIdx.y, s = blockIdx.z;
  if (tid < NC * NC) red[tid] = 0;

  const float* __restrict__ base = coords + (size_t)s * NA * 3;
  const float THR2 = 1.21f;  // 1.1^2

  // Per-thread j-atoms (8 slots, stride 256)
  float xj[JSLOTS], yj[JSLOTS], zj[JSLOTS], tj[JSLOTS];
  int bj[JSLOTS];
#pragma unroll
  for (int u = 0; u < JSLOTS; ++u) {
    int j = jb * JPB + u * THREADS + tid;
    float x = base[3 * j + 0], y = base[3 * j + 1], z = base[3 * j + 2];
    xj[u] = x; yj[u] = y; zj[u] = z;
    tj[u] = x * x + y * y + z * z;
    bj[u] = asym[a2t[j]];
  }
  // Stage i-tile
  if (tid < TI) {
    int i = ib * TI + tid;
    float x = base[3 * i + 0], y = base[3 * i + 1], z = base[3 * i + 2];
    tile[tid] = make_float4(2.0f * x, 2.0f * y, 2.0f * z, THR2 - (x * x + y * y + z * z));
    tchain[tid] = asym[a2t[i]];
  }
  __syncthreads();

  // Is chain_i uniform over the whole tile? (true for this data: 1024-aligned chains)
  int uni_a = __syncthreads_and(tchain[tid & (TI - 1)] == tchain[0]);

  // clash  <=>  d2 < thr2  <=>  2*dot + (thr2 - sq_i) > sq_j
  if (uni_a) {
    int acc[JSLOTS];
#pragma unroll
    for (int u = 0; u < JSLOTS; ++u) acc[u] = 0;
#pragma unroll 4
    for (int t = 0; t < TI; ++t) {
      float4 ci = tile[t];
#pragma unroll
      for (int u = 0; u < JSLOTS; ++u) {
        float d = fmaf(ci.x, xj[u], fmaf(ci.y, yj[u], fmaf(ci.z, zj[u], ci.w)));
        acc[u] += (d > tj[u]);
      }
    }
    const int A = tchain[0];
    // one merge per block: per-slot wave butterfly + single LDS atomic
#pragma unroll
    for (int u = 0; u < JSLOTS; ++u) {
      int v = acc[u];
      int b0 = __builtin_amdgcn_readfirstlane(bj[u]);
      if (__all(bj[u] == b0)) {
#pragma unroll
        for (int m = 32; m >= 1; m >>= 1) v += __shfl_xor(v, m, 64);
        if ((tid & 63) == 0 && v) atomicAdd(&red[A * NC + b0], v);
      } else if (v) {
        atomicAdd(&red[A * NC + bj[u]], v);
      }
    }
  } else {
    // robustness path (not hit with this data layout)
    for (int t = 0; t < TI; ++t) {
      int a = tchain[t];
      float4 ci = tile[t];
#pragma unroll
      for (int u = 0; u < JSLOTS; ++u) {
        float d = fmaf(ci.x, xj[u], fmaf(ci.y, yj[u], fmaf(ci.z, zj[u], ci.w)));
        if (d > tj[u]) atomicAdd(&red[a * NC + bj[u]], 1);
      }
    }
  }

  __syncthreads();
  if (tid < NC * NC) {
    int v = red[tid];
    if (v) atomicAdd(&counts[s * NC * NC + tid], v);
  }
}

__global__ __launch_bounds__(THREADS)
void finalize_kernel(const int* __restrict__ asym, const int* __restrict__ counts,
                     float* __restrict__ out) {
  __shared__ int hist[NC];
  int tid = threadIdx.x;
  if (tid < NC) hist[tid] = 0;
  __syncthreads();
  for (int t = tid; t < NTOK; t += THREADS) atomicAdd(&hist[asym[t]], NA / NTOK);
  __syncthreads();

  // tid = s*64 + a*8 + b  (256 threads cover all entries)
  int c = counts[tid];
  int a = (tid >> 3) & 7, b = tid & 7;
  float total = (a == b) ? 0.0f : (float)c;
  float minn = (float)min(hist[a], hist[b]);
  float rel = total / minn;
  out[tid] = ((total > 100.0f) || (rel > 0.5f)) ? 1.0f : 0.0f;
  out[256 + 2 * tid + 0] = total;
  out[256 + 2 * tid + 1] = rel;
}

extern "C" void kernel_launch(void* const* d_in, const int* in_sizes, int n_in,
                              void* d_out, int out_size, void* d_ws, size_t ws_size,
                              hipStream_t stream) {
  const float* coords = (const float*)d_in[0];  // [4, 8192, 3] f32
  const int* asym = (const int*)d_in[1];        // [1024] i32
  const int* a2t = (const int*)d_in[2];         // [8192] i32
  float* out = (float*)d_out;                   // 256 flags + 512 details

  int* counts = (int*)d_ws;  // [4*8*8]

  hipMemsetAsync(counts, 0, NS * NC * NC * sizeof(int), stream);
  clash_kernel<<<dim3(NIB, NJB, NS), THREADS, 0, stream>>>(coords, asym, a2t, counts);
  finalize_kernel<<<1, THREADS, 0, stream>>>(asym, counts, out);
}

// Round 4
// 92.062 us; speedup vs baseline: 2.5008x; 1.0161x over previous
//
#include <hip/hip_runtime.h>

// Problem constants (fixed by the reference).
#define NS 4
#define NA 8192
#define NTOK 1024
#define NC 8
#define THREADS 256
#define JSLOTS 4
#define JPB (THREADS * JSLOTS)   // 1024 j-atoms per block
#define TI 128                   // i-atoms per block (within one chain segment)
#define NJB (NA / JPB)           // 8
#define NIB (NA / TI)            // 64

// ws: counts[NS*NC*NC] ints, zeroed via hipMemsetAsync before clash_kernel.

__global__ __launch_bounds__(THREADS, 8)
void clash_kernel(const float* __restrict__ coords, const int* __restrict__ asym,
                  const int* __restrict__ a2t, int* __restrict__ counts) {
  __shared__ float4 tile[TI];     // (2x, 2y, 2z, thr^2 - sq) per i-atom
  __shared__ int tchain[TI];
  __shared__ int red[NC * NC];

  const int tid = threadIdx.x;
  const int ib = blockIdx.x, jb = blockIdx.y, s = blockIdx.z;
  if (tid < NC * NC) red[tid] = 0;

  const float* __restrict__ base = coords + (size_t)s * NA * 3;
  const float THR2 = 1.21f;  // 1.1^2

  // Per-thread j-atoms (4 slots, stride 256)
  float xj[JSLOTS], yj[JSLOTS], zj[JSLOTS], tj[JSLOTS];
  int bj[JSLOTS];
#pragma unroll
  for (int u = 0; u < JSLOTS; ++u) {
    int j = jb * JPB + u * THREADS + tid;
    float x = base[3 * j + 0], y = base[3 * j + 1], z = base[3 * j + 2];
    xj[u] = x; yj[u] = y; zj[u] = z;
    tj[u] = x * x + y * y + z * z;
    bj[u] = asym[a2t[j]];
  }
  // Stage i-tile
  if (tid < TI) {
    int i = ib * TI + tid;
    float x = base[3 * i + 0], y = base[3 * i + 1], z = base[3 * i + 2];
    tile[tid] = make_float4(2.0f * x, 2.0f * y, 2.0f * z, THR2 - (x * x + y * y + z * z));
    tchain[tid] = asym[a2t[i]];
  }
  __syncthreads();

  // Is chain_i uniform over the whole tile? (true here: chains are 1024-aligned)
  int uni_a = __syncthreads_and(tchain[tid & (TI - 1)] == tchain[0]);

  // clash  <=>  d2 < thr2  <=>  2*dot + (thr2 - sq_i) > sq_j
  if (uni_a) {
    int acc[JSLOTS];
#pragma unroll
    for (int u = 0; u < JSLOTS; ++u) acc[u] = 0;
#pragma unroll 8
    for (int t = 0; t < TI; ++t) {
      float4 ci = tile[t];
#pragma unroll
      for (int u = 0; u < JSLOTS; ++u) {
        float d = fmaf(ci.x, xj[u], fmaf(ci.y, yj[u], fmaf(ci.z, zj[u], ci.w)));
        acc[u] += (d > tj[u]);
      }
    }
    const int A = tchain[0];
    // one merge per block: per-slot wave butterfly + single LDS atomic
#pragma unroll
    for (int u = 0; u < JSLOTS; ++u) {
      int v = acc[u];
      int b0 = __builtin_amdgcn_readfirstlane(bj[u]);
      if (__all(bj[u] == b0)) {
#pragma unroll
        for (int m = 32; m >= 1; m >>= 1) v += __shfl_xor(v, m, 64);
        if ((tid & 63) == 0 && v) atomicAdd(&red[A * NC + b0], v);
      } else if (v) {
        atomicAdd(&red[A * NC + bj[u]], v);
      }
    }
  } else {
    // robustness path (not hit with this data layout)
    for (int t = 0; t < TI; ++t) {
      int a = tchain[t];
      float4 ci = tile[t];
#pragma unroll
      for (int u = 0; u < JSLOTS; ++u) {
        float d = fmaf(ci.x, xj[u], fmaf(ci.y, yj[u], fmaf(ci.z, zj[u], ci.w)));
        if (d > tj[u]) atomicAdd(&red[a * NC + bj[u]], 1);
      }
    }
  }

  __syncthreads();
  if (tid < NC * NC) {
    int v = red[tid];
    if (v) atomicAdd(&counts[s * NC * NC + tid], v);
  }
}

__global__ __launch_bounds__(THREADS)
void finalize_kernel(const int* __restrict__ asym, const int* __restrict__ counts,
                     float* __restrict__ out) {
  __shared__ int hist[NC];
  int tid = threadIdx.x;
  if (tid < NC) hist[tid] = 0;
  __syncthreads();
  for (int t = tid; t < NTOK; t += THREADS) atomicAdd(&hist[asym[t]], NA / NTOK);
  __syncthreads();

  // tid = s*64 + a*8 + b  (256 threads cover all entries)
  int c = counts[tid];
  int a = (tid >> 3) & 7, b = tid & 7;
  float total = (a == b) ? 0.0f : (float)c;
  float minn = (float)min(hist[a], hist[b]);
  float rel = total / minn;
  out[tid] = ((total > 100.0f) || (rel > 0.5f)) ? 1.0f : 0.0f;
  out[256 + 2 * tid + 0] = total;
  out[256 + 2 * tid + 1] = rel;
}

extern "C" void kernel_launch(void* const* d_in, const int* in_sizes, int n_in,
                              void* d_out, int out_size, void* d_ws, size_t ws_size,
                              hipStream_t stream) {
  const float* coords = (const float*)d_in[0];  // [4, 8192, 3] f32
  const int* asym = (const int*)d_in[1];        // [1024] i32
  const int* a2t = (const int*)d_in[2];         // [8192] i32
  float* out = (float*)d_out;                   // 256 flags + 512 details

  int* counts = (int*)d_ws;  // [4*8*8]

  hipMemsetAsync(counts, 0, NS * NC * NC * sizeof(int), stream);
  clash_kernel<<<dim3(NIB, NJB, NS), THREADS, 0, stream>>>(coords, asym, a2t, counts);
  finalize_kernel<<<1, THREADS, 0, stream>>>(asym, counts, out);
}